// Round 8
// baseline (55.600 us; speedup 1.0000x reference)
//
#include <hip/hip_runtime.h>

#define NB 10

typedef float f32x4 __attribute__((ext_vector_type(4)));

// Volatile asm load with 'sc1 nt': sc1 -> serve the read via the coherence
// point, bypassing the per-XCD L2 whose allocate/evict path is the suspected
// 5.6 TB/s cap on this zero-reuse stream; nt -> no-allocate hint. Volatile
// also stops the scheduler re-serializing the in-flight batch (R2 lesson).
__device__ __forceinline__ f32x4 async_load_nt(const float* p) {
    f32x4 r;
    asm volatile("global_load_dwordx4 %0, %1, off sc1 nt"
                 : "=v"(r)
                 : "v"(p)
                 : "memory");
    return r;
}

__device__ __forceinline__ void accum_pair(const f32x4 c, const f32x4 k,
                                           float acc[NB]) {
#pragma unroll
    for (int e = 0; e < 4; ++e) {
        const int idx = (int)(c[e] * (float)NB);  // conf >= 0: trunc == floor
        const float d = c[e] - k[e];
#pragma unroll
        for (int j = 0; j < NB; ++j)
            acc[j] += (idx == j) ? d : 0.0f;  // idx>=10 (overflow bin) dropped
    }
}

// Stage 1: per-block bin sums of (conf - correct), plain stores of partials.
// (R5/R6: fusion loses to XCD-coherence costs; two kernels is the right
// structure. R4: no global atomics — single-line atomic tail cost ~9us.)
__global__ __launch_bounds__(256) void ece_partial_kernel(
    const float* __restrict__ conf, const float* __restrict__ corr,
    float* __restrict__ ws, int n)
{
    float acc[NB];
#pragma unroll
    for (int j = 0; j < NB; ++j) acc[j] = 0.0f;

    const int tid = threadIdx.x;
    const int gid = blockIdx.x * blockDim.x + tid;
    const int stride = gridDim.x * blockDim.x;  // in float4 units
    const int n4 = n >> 2;

    int i = gid;

    for (; i + 3 * stride < n4; i += 4 * stride) {
        const float* cb = conf + 4ll * i;
        const float* kb = corr + 4ll * i;
        const long long soff = 4ll * stride;

        f32x4 c0 = async_load_nt(cb);
        f32x4 k0 = async_load_nt(kb);
        f32x4 c1 = async_load_nt(cb + soff);
        f32x4 k1 = async_load_nt(kb + soff);
        f32x4 c2 = async_load_nt(cb + 2 * soff);
        f32x4 k2 = async_load_nt(kb + 2 * soff);
        f32x4 c3 = async_load_nt(cb + 3 * soff);
        f32x4 k3 = async_load_nt(kb + 3 * soff);

        asm volatile("s_waitcnt vmcnt(4)" ::: "memory");
        __builtin_amdgcn_sched_barrier(0);
        accum_pair(c0, k0, acc);
        accum_pair(c1, k1, acc);

        asm volatile("s_waitcnt vmcnt(0)" ::: "memory");
        __builtin_amdgcn_sched_barrier(0);
        accum_pair(c2, k2, acc);
        accum_pair(c3, k3, acc);
    }

    for (; i < n4; i += stride) {
        const f32x4 c = *reinterpret_cast<const f32x4*>(conf + 4ll * i);
        const f32x4 k = *reinterpret_cast<const f32x4*>(corr + 4ll * i);
        accum_pair(c, k, acc);
    }

    if (gid == 0) {
        for (int t = (n4 << 2); t < n; ++t) {
            const float cv = conf[t];
            const int idx = (int)(cv * (float)NB);
            const float d = cv - corr[t];
#pragma unroll
            for (int j = 0; j < NB; ++j)
                acc[j] += (idx == j) ? d : 0.0f;
        }
    }

    // block reduction: [bin][tid] layout -> bank = tid%32, conflict-free
    __shared__ float red[NB][256];
#pragma unroll
    for (int j = 0; j < NB; ++j) red[j][tid] = acc[j];
    __syncthreads();

    for (int s = 128; s > 0; s >>= 1) {
        if (tid < s) {
#pragma unroll
            for (int j = 0; j < NB; ++j) red[j][tid] += red[j][tid + s];
        }
        __syncthreads();
    }

    // bin-major partials so stage 2 reads are coalesced
    if (tid < NB) ws[tid * gridDim.x + blockIdx.x] = red[tid][0];
}

// Stage 2: reduce nblk x NB partials, ece = sum_j |sum_b ws[j][b]| / n
__global__ __launch_bounds__(1024) void ece_final_kernel(
    const float* __restrict__ ws, float* __restrict__ out, int n, int nblk)
{
    const int tid = threadIdx.x;
    float acc[NB];
#pragma unroll
    for (int j = 0; j < NB; ++j) acc[j] = 0.0f;

    for (int i = tid; i < nblk; i += 1024) {
#pragma unroll
        for (int j = 0; j < NB; ++j) acc[j] += ws[j * nblk + i];
    }

    __shared__ float red[NB][1024];
#pragma unroll
    for (int j = 0; j < NB; ++j) red[j][tid] = acc[j];
    __syncthreads();

    for (int s = 512; s > 0; s >>= 1) {
        if (tid < s) {
#pragma unroll
            for (int j = 0; j < NB; ++j) red[j][tid] += red[j][tid + s];
        }
        __syncthreads();
    }

    if (tid == 0) {
        float s = 0.0f;
#pragma unroll
        for (int j = 0; j < NB; ++j) s += fabsf(red[j][0]);
        out[0] = s / (float)n;
    }
}

extern "C" void kernel_launch(void* const* d_in, const int* in_sizes, int n_in,
                              void* d_out, int out_size, void* d_ws, size_t ws_size,
                              hipStream_t stream) {
    const float* conf = (const float*)d_in[0];
    const float* corr = (const float*)d_in[1];
    float* ws = (float*)d_ws;
    float* out = (float*)d_out;
    const int n = in_sizes[0];

    const int n4 = n >> 2;
    int blocks = (n4 + 255) / 256;
    if (blocks > 2048) blocks = 2048;
    // safety: ws must hold blocks*NB floats
    const int maxblk = (int)(ws_size / (NB * sizeof(float)));
    if (blocks > maxblk) blocks = maxblk;
    if (blocks < 1) blocks = 1;

    ece_partial_kernel<<<blocks, 256, 0, stream>>>(conf, corr, ws, n);
    ece_final_kernel<<<1, 1024, 0, stream>>>(ws, out, n, blocks);
}